// Round 4
// baseline (277.889 us; speedup 1.0000x reference)
//
#include <hip/hip_runtime.h>

// out[r,d] = ((x[r]*W[d] + b[d])*32 - mean_r) * rsqrt(var_r + 1e-5) * gamma[d] + beta[d]
// Closed form: mean_r, var_r depend only on scalar x[r] and the moments of W,b:
//   mean = 32*(x*mW + mB)
//   var  = 1024*(x^2*varW + 2x*cov(W,b) + varB)
// Standardized rewrite (no mean in inner loop):
//   out = s * (x*(W-mW)*g + (b-mB)*g) + beta,  s = 32*rsqrt(var+eps)
// Single kernel: each block redundantly reduces the 5 W/b moments (cheap,
// fully parallel), then streams 32 rows of float4 nontemporal stores.

#define D_SIZE   1024
#define N_ROWS   65536          // BATCH(2048) * NUM_NODES(32)
#define SCALE_F  32.0f          // sqrt(1024)
#define LN_EPS_F 1e-5f
#define GRID_N   2048

typedef float vfloat4 __attribute__((ext_vector_type(4)));

__global__ __launch_bounds__(256, 8)
void fused_expand_ln_kernel(const float* __restrict__ x,
                            const float* __restrict__ W,
                            const float* __restrict__ bias,
                            const float* __restrict__ gamma,
                            const float* __restrict__ beta,
                            float* __restrict__ out) {
    const int t  = threadIdx.x;
    const int d0 = t * 4;

    const vfloat4 W4 = *reinterpret_cast<const vfloat4*>(W     + d0);
    const vfloat4 B4 = *reinterpret_cast<const vfloat4*>(bias  + d0);
    const vfloat4 G4 = *reinterpret_cast<const vfloat4*>(gamma + d0);
    const vfloat4 E4 = *reinterpret_cast<const vfloat4*>(beta  + d0);

    // ---- per-block redundant reduction of 5 moments over 1024 elems ----
    float sW  = W4.x + W4.y + W4.z + W4.w;
    float sB  = B4.x + B4.y + B4.z + B4.w;
    float sW2 = W4.x*W4.x + W4.y*W4.y + W4.z*W4.z + W4.w*W4.w;
    float sB2 = B4.x*B4.x + B4.y*B4.y + B4.z*B4.z + B4.w*B4.w;
    float sWB = W4.x*B4.x + W4.y*B4.y + W4.z*B4.z + W4.w*B4.w;

    #pragma unroll
    for (int off = 32; off > 0; off >>= 1) {
        sW  += __shfl_down(sW,  off);
        sB  += __shfl_down(sB,  off);
        sW2 += __shfl_down(sW2, off);
        sB2 += __shfl_down(sB2, off);
        sWB += __shfl_down(sWB, off);
    }

    __shared__ float red[4][5];
    const int wave = t >> 6;
    if ((t & 63) == 0) {
        red[wave][0] = sW;  red[wave][1] = sB;  red[wave][2] = sW2;
        red[wave][3] = sB2; red[wave][4] = sWB;
    }
    __syncthreads();
    sW  = red[0][0] + red[1][0] + red[2][0] + red[3][0];
    sB  = red[0][1] + red[1][1] + red[2][1] + red[3][1];
    sW2 = red[0][2] + red[1][2] + red[2][2] + red[3][2];
    sB2 = red[0][3] + red[1][3] + red[2][3] + red[3][3];
    sWB = red[0][4] + red[1][4] + red[2][4] + red[3][4];

    const float inv_d  = 1.0f / (float)D_SIZE;
    const float mW     = sW * inv_d;
    const float mB     = sB * inv_d;
    const float varW   = sW2 * inv_d - mW * mW;
    const float varB   = sB2 * inv_d - mB * mB;
    const float covWB  = sWB * inv_d - mW * mB;

    // per-thread fused constants: A = (W-mW)*g, C = (b-mB)*g
    vfloat4 A4, C4;
    A4.x = (W4.x - mW) * G4.x;  C4.x = (B4.x - mB) * G4.x;
    A4.y = (W4.y - mW) * G4.y;  C4.y = (B4.y - mB) * G4.y;
    A4.z = (W4.z - mW) * G4.z;  C4.z = (B4.z - mB) * G4.z;
    A4.w = (W4.w - mW) * G4.w;  C4.w = (B4.w - mB) * G4.w;

    const float vscale = SCALE_F * SCALE_F;   // 1024

    // ---- stream rows: 2 FMAs per element + float4 nontemporal store ----
    for (int row = blockIdx.x; row < N_ROWS; row += GRID_N) {
        const float xv  = x[row];   // block-uniform -> scalar load
        const float var = vscale * (xv * xv * varW + 2.0f * xv * covWB + varB);
        const float s   = SCALE_F * rsqrtf(var + LN_EPS_F);

        vfloat4 o;
        o.x = fmaf(s, fmaf(xv, A4.x, C4.x), E4.x);
        o.y = fmaf(s, fmaf(xv, A4.y, C4.y), E4.y);
        o.z = fmaf(s, fmaf(xv, A4.z, C4.z), E4.z);
        o.w = fmaf(s, fmaf(xv, A4.w, C4.w), E4.w);

        __builtin_nontemporal_store(o, reinterpret_cast<vfloat4*>(
            out + (size_t)row * D_SIZE + d0));
    }
}

extern "C" void kernel_launch(void* const* d_in, const int* in_sizes, int n_in,
                              void* d_out, int out_size, void* d_ws, size_t ws_size,
                              hipStream_t stream) {
    const float* x     = (const float*)d_in[0];   // (2048, 32)
    const float* W     = (const float*)d_in[1];   // (1024, 1)
    const float* bias  = (const float*)d_in[2];   // (1024,)
    const float* gamma = (const float*)d_in[3];   // (1024,)
    const float* beta  = (const float*)d_in[4];   // (1024,)
    float* out = (float*)d_out;                   // (2048, 32, 1024) f32

    fused_expand_ln_kernel<<<GRID_N, 256, 0, stream>>>(x, W, bias, gamma,
                                                       beta, out);
}